// Round 5
// baseline (4561.547 us; speedup 1.0000x reference)
//
#include <hip/hip_runtime.h>
#include <math.h>

// MoE router: X[8192,4096] fp32 @ W^T -> logits[8192,64] -> top2 softmax scatter.
// d_out = probs[8192*64] ++ routing_map[8192*64] (floats).
// ws: part [8][8192][64] fp32 (16MB). Wt (W^T, 1MB) staged in d_out scratch.
//
// R1: lane=token raw X reads -> 4x overfetch. Fixed via LDS staging.
// R2: 96us. lane=token + SMEM W: per-k lgkmcnt(0) drain ~300cy vs 128cy FMA
//     -> duty 30%, 1 wave/SIMD.
// R3 FAILED: 2 tokens/lane -> ~170 live VGPRs -> scratch. acc<=64.
// R4 FAILED: W via per-j ds_read_b128 broadcast -> DS-instr flood.
// R5: 8x8 reg-tile outer product, x+w via LDS. 92us, VALUBusy 40%.
// R6: +1 wave/SIMD: ZERO gain. DS *bandwidth* arithmetic says DS was never
//     saturated (2.5 vs 112 B/cyc/CU) -> R5/R6 stuck on per-k lgkm latency.
// R7 FAILED: SGPR-W structure + __launch_bounds__(256,4): VGPR cap 128 ->
//     allocator collapsed to 64 VGPRs, acc[64] spilled to scratch: 12.6GB
//     HBM scratch traffic, 4.1ms. Structure untested.
// R8: same structure, __launch_bounds__(256,2): budget 256 -> ~110 VGPRs,
//     no spill; HW occupancy from actual count (<=128 -> 4 waves/SIMD, LDS
//     135KB/CU ok). Per-wave duty ~30% x4 waves -> predict VALUBusy 75-90%,
//     logits ~40us.

#define HDIM 4096
#define NEXP 64
#define NTOK 8192
#define HG 8
#define HSLAB (HDIM / HG)      // 512 k per block
#define WAVES 4
#define KWAVE (HSLAB / WAVES)  // 128 k per wave
#define KK 16                  // k per staged chunk
#define NCH (KWAVE / KK)       // 8 chunks per wave
#define XS2 66                 // staging row stride (floats), ~2-way banks
#define SRS 65                 // reduce buf stride, [j][t] layout, 2-way banks

// ---------------- kernel 0: W[64][4096] -> Wt[4096][64] ----------------
__global__ __launch_bounds__(64) void wtrans_kernel(
        const float* __restrict__ W, float* __restrict__ Wt) {
    __shared__ float t[64][65];
    const int kb = blockIdx.x * 64;
    const int lane = threadIdx.x;          // = expert e
    #pragma unroll
    for (int q = 0; q < 16; ++q) {         // read own W row, 16B chunks
        float4 v = *reinterpret_cast<const float4*>(W + (size_t)lane * HDIM + kb + q * 4);
        t[lane][q * 4 + 0] = v.x; t[lane][q * 4 + 1] = v.y;
        t[lane][q * 4 + 2] = v.z; t[lane][q * 4 + 3] = v.w;
    }
    __syncthreads();
    #pragma unroll 4
    for (int k = 0; k < 64; ++k)           // coalesced 64-lane row writes
        Wt[(size_t)(kb + k) * NEXP + lane] = t[lane][k];
}

// ---------------- kernel 1: partial logits ----------------
__global__ __launch_bounds__(256, 2) void logits_kernel(
        const float* __restrict__ X, const float* __restrict__ Wt,
        float* __restrict__ part) {
    const int tg   = blockIdx.x >> 3;      // 0..127
    const int hg   = blockIdx.x & 7;       // 0..7
    const int wav  = threadIdx.x >> 6;     // 0..3 : k-sub-slab owner
    const int lane = threadIdx.x & 63;     // = token within 64-token tile

    __shared__ __align__(16) float sred[NEXP * SRS];        // 16640B reduce buf
    __shared__ __align__(16) float sstg[WAVES][KK * XS2];   // 4*4224B staging

    float* xs = sstg[wav];                 // wave-private: NO barriers in loop
    const int token0 = tg * 64;
    const int kbase  = hg * HSLAB + wav * KWAVE;

    const int r4 = lane >> 2;              // 0..15
    const int sl = lane & 3;               // 0..3

    float acc[NEXP];
    #pragma unroll
    for (int j = 0; j < NEXP; ++j) acc[j] = 0.f;

    const float* Xb = X + (size_t)token0 * HDIM + kbase;

    float4 pfx[4];
    // ---- prologue: load + scatter chunk 0 (64 tokens x 16 k, k-major) ----
    #pragma unroll
    for (int p = 0; p < 4; ++p)
        pfx[p] = *reinterpret_cast<const float4*>(Xb + (size_t)(p * 16 + r4) * HDIM + sl * 4);
    #pragma unroll
    for (int p = 0; p < 4; ++p) {
        int row = p * 16 + r4;
        xs[(sl * 4 + 0) * XS2 + row] = pfx[p].x;
        xs[(sl * 4 + 1) * XS2 + row] = pfx[p].y;
        xs[(sl * 4 + 2) * XS2 + row] = pfx[p].z;
        xs[(sl * 4 + 3) * XS2 + row] = pfx[p].w;
    }

    for (int c = 0; c < NCH; ++c) {
        if (c + 1 < NCH) {                 // global prefetch of next chunk
            const int off = (c + 1) * KK;
            #pragma unroll
            for (int p = 0; p < 4; ++p)
                pfx[p] = *reinterpret_cast<const float4*>(
                    Xb + (size_t)(p * 16 + r4) * HDIM + off + sl * 4);
        }
        // ---- compute: per k, 1 ds_read_b32 (x) + 64 FMAs (w from SGPRs) ----
        const float* wrow = Wt + (size_t)(kbase + c * KK) * NEXP;
        #pragma unroll
        for (int k = 0; k < KK; ++k) {
            float xk = xs[k * XS2 + lane];             // broadcast-free, 2-way banks
            const float* wr = wrow + k * NEXP;         // uniform -> s_load_dwordx16 x4
            #pragma unroll
            for (int j = 0; j < NEXP; ++j)
                acc[j] = fmaf(xk, wr[j], acc[j]);
        }
        if (c + 1 < NCH) {                 // commit prefetched chunk (same wave:
            #pragma unroll                 // program order, no barrier needed)
            for (int p = 0; p < 4; ++p) {
                int row = p * 16 + r4;
                xs[(sl * 4 + 0) * XS2 + row] = pfx[p].x;
                xs[(sl * 4 + 1) * XS2 + row] = pfx[p].y;
                xs[(sl * 4 + 2) * XS2 + row] = pfx[p].z;
                xs[(sl * 4 + 3) * XS2 + row] = pfx[p].w;
            }
        }
    }

    // ---- epilogue: sequential 4-wave reduce in LDS ([j][t], 2-way banks) ----
    __syncthreads();
    if (wav == 3) {
        #pragma unroll
        for (int j = 0; j < NEXP; ++j) sred[j * SRS + lane] = acc[j];
    }
    __syncthreads();
    if (wav == 2) {
        #pragma unroll
        for (int j = 0; j < NEXP; ++j) sred[j * SRS + lane] += acc[j];
    }
    __syncthreads();
    if (wav == 1) {
        #pragma unroll
        for (int j = 0; j < NEXP; ++j) sred[j * SRS + lane] += acc[j];
    }
    __syncthreads();
    if (wav == 0) {
        #pragma unroll
        for (int j = 0; j < NEXP; ++j) acc[j] += sred[j * SRS + lane];
        float* dst = part + ((size_t)hg * NTOK + token0 + lane) * NEXP;
        #pragma unroll
        for (int q = 0; q < 16; ++q)
            *reinterpret_cast<float4*>(dst + q * 4) =
                make_float4(acc[q * 4 + 0], acc[q * 4 + 1],
                            acc[q * 4 + 2], acc[q * 4 + 3]);
    }
}

// ---------------- kernel 2: reduce HG partials, top-2 softmax, scatter ----------------
__global__ __launch_bounds__(256) void topk_kernel(
        const float* __restrict__ part, float* __restrict__ probs,
        float* __restrict__ rmap) {
    const int wave = threadIdx.x >> 6;
    const int lane = threadIdx.x & 63;       // lane = expert
    const int token = blockIdx.x * 4 + wave;

    const float* p = part + (size_t)token * NEXP + lane;
    float v = 0.f;
    #pragma unroll
    for (int hg = 0; hg < HG; ++hg) v += p[(size_t)hg * NTOK * NEXP];

    // top-1 (lower index wins ties, like lax.top_k)
    float m1 = v; int i1 = lane;
    #pragma unroll
    for (int s = 32; s > 0; s >>= 1) {
        float om = __shfl_xor(m1, s, 64);
        int   oi = __shfl_xor(i1, s, 64);
        if (om > m1 || (om == m1 && oi < i1)) { m1 = om; i1 = oi; }
    }
    // top-2: exclude i1
    float vx = (lane == i1) ? -INFINITY : v;
    float m2 = vx; int i2 = lane;
    #pragma unroll
    for (int s = 32; s > 0; s >>= 1) {
        float om = __shfl_xor(m2, s, 64);
        int   oi = __shfl_xor(i2, s, 64);
        if (om > m2 || (om == m2 && oi < i2)) { m2 = om; i2 = oi; }
    }

    float e2 = expf(m2 - m1);
    float p1 = 1.f / (1.f + e2);
    float p2 = 1.f - p1;

    float prob = (lane == i1) ? p1 : ((lane == i2) ? p2 : 0.f);
    float flag = (lane == i1 || lane == i2) ? 1.f : 0.f;
    probs[(size_t)token * NEXP + lane] = prob;
    rmap [(size_t)token * NEXP + lane] = flag;
}

extern "C" void kernel_launch(void* const* d_in, const int* in_sizes, int n_in,
                              void* d_out, int out_size, void* d_ws, size_t ws_size,
                              hipStream_t stream) {
    const float* X = (const float*)d_in[0];   // [8192,4096]
    const float* W = (const float*)d_in[1];   // [64,4096]
    float* out  = (float*)d_out;
    float* part = (float*)d_ws;               // [8][8192][64] floats = 16MB
    float* Wt   = out;                        // 4096*64 floats = 1MB scratch in
                                              // d_out; fully overwritten by topk.

    wtrans_kernel<<<HDIM / 64, 64, 0, stream>>>(W, Wt);
    logits_kernel<<<128 * HG, 256, 0, stream>>>(X, Wt, part);
    topk_kernel<<<NTOK / 4, 256, 0, stream>>>(part, out, out + (size_t)NTOK * NEXP);
}

// Round 6
// 227.662 us; speedup vs baseline: 20.0364x; 20.0364x over previous
//
#include <hip/hip_runtime.h>
#include <math.h>

// MoE router: X[8192,4096] fp32 @ W^T -> logits[8192,64] -> top2 softmax scatter.
// d_out = probs[8192*64] ++ routing_map[8192*64] (floats).
// ws: part [8][8192][64] fp32 (16MB)
//
// R1: lane=token raw X reads -> 4x overfetch. Fixed via LDS staging.
// R2: 96us. lane=token + SMEM W: per-k lgkmcnt(0) drain, duty 30%.
// R3 FAILED: 2 tokens/lane -> ~170 live VGPRs -> scratch. acc<=64.
// R4 FAILED: W via per-j ds_read_b128 broadcast -> DS-instr flood.
// R5: 8x8 reg-tile outer product, x+w via LDS, 1-wave blocks. 92us,
//     VALUBusy 41%: loads of step k consumed immediately -> ~156cy LDS
//     latency tail exposed every k (128 FMA-cyc only partially covers).
// R6: +1 wave/SIMD: ZERO gain (DS instr pressure doubles too; ~same 41%).
// R7/R8 FAILED: acc[64] + 64-wide W operand always loses regalloc (12.6GB /
//     11.3GB scratch spill). SGPR-W family dead.
// R9: R5 exact + distance-2 software pipeline of fragment loads: 3-slot
//     rotating frag regs (const idx after unroll), load k+2 under FMA k ->
//     counted lgkmcnt(8), 256 FMA-cyc cover ~156cy latency. Predict
//     VALUBusy 60-75%, logits 50-65us.

#define HDIM 4096
#define NEXP 64
#define NTOK 8192
#define HG 8
#define HSLAB (HDIM / HG)   // 512 k per block
#define KK 16               // k per staged chunk
#define NCH (HSLAB / KK)    // 32 chunks
#define TPBK 64             // tokens per block (wave)
#define XS 68               // LDS row stride (floats): rows 16B-aligned, ~2-way banks

// ---------------- kernel 1: partial logits ----------------
__global__ __launch_bounds__(64) void logits_kernel(
        const float* __restrict__ X, const float* __restrict__ W,
        float* __restrict__ part) {
    const int tg   = blockIdx.x >> 3;   // 0..127
    const int hg   = blockIdx.x & 7;    // 0..7
    const int lane = threadIdx.x;       // 0..63
    const int tr   = lane >> 3;         // token-row group 0..7
    const int ec   = lane & 7;          // expert-col group 0..7

    __shared__ __align__(16) float smem[2 * KK * XS];   // 8704 B
    float* xs = smem;                   // [KK][XS]: xs[k][token]
    float* ws = smem + KK * XS;         // [KK][XS]: ws[k][expert]

    const int token0 = tg * TPBK;
    const int hbase  = hg * HSLAB;

    const int r4 = lane >> 2;           // 0..15
    const int sl = lane & 3;            // 0..3

    float acc[8][8];
    #pragma unroll
    for (int i = 0; i < 8; ++i)
        #pragma unroll
        for (int j = 0; j < 8; ++j) acc[i][j] = 0.f;

    const float* Xb = X + (size_t)token0 * HDIM + hbase;

    float4 pfx[4], pfw[4];
    // ---- prologue: load + store chunk 0 ----
    #pragma unroll
    for (int p = 0; p < 4; ++p) {       // x tile 64t x 16k, coalesced 4 lanes/row
        int row = p * 16 + r4;
        pfx[p] = *reinterpret_cast<const float4*>(Xb + (size_t)row * HDIM + sl * 4);
    }
    #pragma unroll
    for (int q = 0; q < 4; ++q) {       // w tile 64e x 16k, coalesced 4 lanes/row
        int idx = q * 64 + lane;
        int e = idx >> 2, s2 = idx & 3;
        pfw[q] = *reinterpret_cast<const float4*>(W + (size_t)e * HDIM + hbase + s2 * 4);
    }
    #pragma unroll
    for (int p = 0; p < 4; ++p) {       // transpose-scatter to k-major (~2-way banks)
        int row = p * 16 + r4;
        xs[(sl * 4 + 0) * XS + row] = pfx[p].x;
        xs[(sl * 4 + 1) * XS + row] = pfx[p].y;
        xs[(sl * 4 + 2) * XS + row] = pfx[p].z;
        xs[(sl * 4 + 3) * XS + row] = pfx[p].w;
    }
    #pragma unroll
    for (int q = 0; q < 4; ++q) {
        int idx = q * 64 + lane;
        int e = idx >> 2, s2 = idx & 3;
        ws[(s2 * 4 + 0) * XS + e] = pfw[q].x;
        ws[(s2 * 4 + 1) * XS + e] = pfw[q].y;
        ws[(s2 * 4 + 2) * XS + e] = pfw[q].z;
        ws[(s2 * 4 + 3) * XS + e] = pfw[q].w;
    }
    __syncthreads();                    // single wave: trivial, just orders LDS

    for (int c = 0; c < NCH; ++c) {
        if (c + 1 < NCH) {              // global prefetch of next chunk (hidden)
            const int off = (c + 1) * KK;
            #pragma unroll
            for (int p = 0; p < 4; ++p) {
                int row = p * 16 + r4;
                pfx[p] = *reinterpret_cast<const float4*>(
                    Xb + (size_t)row * HDIM + off + sl * 4);
            }
            #pragma unroll
            for (int q = 0; q < 4; ++q) {
                int idx = q * 64 + lane;
                int e = idx >> 2, s2 = idx & 3;
                pfw[q] = *reinterpret_cast<const float4*>(
                    W + (size_t)e * HDIM + hbase + off + s2 * 4);
            }
        }
        // ---- compute: distance-2 pipelined: issue ds_reads for k+2 under
        //      FMAs of k (3-slot rotating frag regs, const-folded indices) ----
        {
            float4 fxa[3], fxb[3], fwa[3], fwb[3];
            #pragma unroll
            for (int q = 0; q < 2; ++q) {   // prime slots 0,1 (k=0,1)
                const float4* xr = reinterpret_cast<const float4*>(xs + q * XS + tr * 8);
                const float4* wr = reinterpret_cast<const float4*>(ws + q * XS + ec * 8);
                fxa[q] = xr[0]; fxb[q] = xr[1];
                fwa[q] = wr[0]; fwb[q] = wr[1];
            }
            #pragma unroll
            for (int k = 0; k < KK; ++k) {
                const int cur = k % 3;
                if (k + 2 < KK) {
                    const int nxt = (k + 2) % 3;
                    const float4* xr = reinterpret_cast<const float4*>(xs + (k + 2) * XS + tr * 8);
                    const float4* wr = reinterpret_cast<const float4*>(ws + (k + 2) * XS + ec * 8);
                    fxa[nxt] = xr[0]; fxb[nxt] = xr[1];
                    fwa[nxt] = wr[0]; fwb[nxt] = wr[1];
                }
                float xv[8] = {fxa[cur].x, fxa[cur].y, fxa[cur].z, fxa[cur].w,
                               fxb[cur].x, fxb[cur].y, fxb[cur].z, fxb[cur].w};
                float wv[8] = {fwa[cur].x, fwa[cur].y, fwa[cur].z, fwa[cur].w,
                               fwb[cur].x, fwb[cur].y, fwb[cur].z, fwb[cur].w};
                #pragma unroll
                for (int i = 0; i < 8; ++i)
                    #pragma unroll
                    for (int j = 0; j < 8; ++j)
                        acc[i][j] = fmaf(xv[i], wv[j], acc[i][j]);
            }
        }
        __syncthreads();
        if (c + 1 < NCH) {              // commit prefetched chunk to LDS
            #pragma unroll
            for (int p = 0; p < 4; ++p) {
                int row = p * 16 + r4;
                xs[(sl * 4 + 0) * XS + row] = pfx[p].x;
                xs[(sl * 4 + 1) * XS + row] = pfx[p].y;
                xs[(sl * 4 + 2) * XS + row] = pfx[p].z;
                xs[(sl * 4 + 3) * XS + row] = pfx[p].w;
            }
            #pragma unroll
            for (int q = 0; q < 4; ++q) {
                int idx = q * 64 + lane;
                int e = idx >> 2, s2 = idx & 3;
                ws[(s2 * 4 + 0) * XS + e] = pfw[q].x;
                ws[(s2 * 4 + 1) * XS + e] = pfw[q].y;
                ws[(s2 * 4 + 2) * XS + e] = pfw[q].z;
                ws[(s2 * 4 + 3) * XS + e] = pfw[q].w;
            }
        }
        __syncthreads();
    }

    // ---- epilogue: per lane 8 tokens x 8 consecutive experts, float4 stores ----
    float* dst = part + ((size_t)hg * NTOK + token0) * NEXP;
    #pragma unroll
    for (int i = 0; i < 8; ++i) {
        int t = tr * 8 + i;
        *reinterpret_cast<float4*>(dst + (size_t)t * NEXP + ec * 8) =
            make_float4(acc[i][0], acc[i][1], acc[i][2], acc[i][3]);
        *reinterpret_cast<float4*>(dst + (size_t)t * NEXP + ec * 8 + 4) =
            make_float4(acc[i][4], acc[i][5], acc[i][6], acc[i][7]);
    }
}

// ---------------- kernel 2: reduce HG partials, top-2 softmax, scatter ----------------
__global__ __launch_bounds__(256) void topk_kernel(
        const float* __restrict__ part, float* __restrict__ probs,
        float* __restrict__ rmap) {
    const int wave = threadIdx.x >> 6;
    const int lane = threadIdx.x & 63;       // lane = expert
    const int token = blockIdx.x * 4 + wave;

    const float* p = part + (size_t)token * NEXP + lane;
    float v = 0.f;
    #pragma unroll
    for (int hg = 0; hg < HG; ++hg) v += p[(size_t)hg * NTOK * NEXP];

    // top-1 (lower index wins ties, like lax.top_k)
    float m1 = v; int i1 = lane;
    #pragma unroll
    for (int s = 32; s > 0; s >>= 1) {
        float om = __shfl_xor(m1, s, 64);
        int   oi = __shfl_xor(i1, s, 64);
        if (om > m1 || (om == m1 && oi < i1)) { m1 = om; i1 = oi; }
    }
    // top-2: exclude i1
    float vx = (lane == i1) ? -INFINITY : v;
    float m2 = vx; int i2 = lane;
    #pragma unroll
    for (int s = 32; s > 0; s >>= 1) {
        float om = __shfl_xor(m2, s, 64);
        int   oi = __shfl_xor(i2, s, 64);
        if (om > m2 || (om == m2 && oi < i2)) { m2 = om; i2 = oi; }
    }

    float e2 = expf(m2 - m1);
    float p1 = 1.f / (1.f + e2);
    float p2 = 1.f - p1;

    float prob = (lane == i1) ? p1 : ((lane == i2) ? p2 : 0.f);
    float flag = (lane == i1 || lane == i2) ? 1.f : 0.f;
    probs[(size_t)token * NEXP + lane] = prob;
    rmap [(size_t)token * NEXP + lane] = flag;
}

extern "C" void kernel_launch(void* const* d_in, const int* in_sizes, int n_in,
                              void* d_out, int out_size, void* d_ws, size_t ws_size,
                              hipStream_t stream) {
    const float* X = (const float*)d_in[0];   // [8192,4096]
    const float* W = (const float*)d_in[1];   // [64,4096]
    float* out  = (float*)d_out;
    float* part = (float*)d_ws;               // [8][8192][64] floats = 16MB

    logits_kernel<<<128 * HG, 64, 0, stream>>>(X, W, part);
    topk_kernel<<<NTOK / 4, 256, 0, stream>>>(part, out, out + (size_t)NTOK * NEXP);
}